// Round 8
// baseline (122.220 us; speedup 1.0000x reference)
//
#include <hip/hip_runtime.h>

// TuckERInteraction: scores[n'] = sum_i u[n',i] * v[n',i]
//   v[n',i] = sum_j W[n'>>8, i, j] * t_bn[n', j]               (k_A, k = n'>>8)
//   out[n'] = sum_a h_bn[n',a] * (sum_i r[low,a,i] * v[n',i])  (k_B, low = n'&255)
// N = 32768, D = 128. ws: V only (bf16, 8 MB) — proven footprint.
//
// R12 = R10 base (passed) + global_load_lds staging of the shared operands.
//  Ledger: occupancy x2/x3, phase merges, 32-deep register batching all
//  NEUTRAL (114.5-118.5); LDS-free -24%. The one untried ladder step
//  (guide Common-mistake #1, +67% measured on GEMM staging): stage W (A) and
//  r (B) as RAW F32 straight to LDS with global_load_lds width=16 — no VGPR
//  round-trip, no cvt on the staging path. Source-address XOR swizzle
//  (linear LDS dest + pre-swizzled global src, same XOR at read) keeps the
//  f32 fragment reads (512B row stride) at <=4-way conflict instead of
//  16-way. f32->bf16 conversion moves to fragment-read (same f2bf bits;
//  VALU is 5% busy => free). t-frags / V-frags / h-epilogue = R10 verbatim.

typedef __attribute__((ext_vector_type(8))) short bf16x8;   // MFMA A/B fragment (8 bf16)
typedef __attribute__((ext_vector_type(4))) float f32x4;

#define BN_EPS 1e-5f

__device__ inline unsigned short f2bf(float f) {
  unsigned u = __builtin_bit_cast(unsigned, f);
  u += 0x7FFFu + ((u >> 16) & 1u);          // round-to-nearest-even
  return (unsigned short)(u >> 16);
}
__device__ inline unsigned pack2bf(float lo, float hi) {
  return (unsigned)f2bf(lo) | ((unsigned)f2bf(hi) << 16);
}
__device__ inline bf16x8 cvt8(f32x4 lo, f32x4 hi) {
  bf16x8 o;
  o[0] = (short)f2bf(lo[0]); o[1] = (short)f2bf(lo[1]);
  o[2] = (short)f2bf(lo[2]); o[3] = (short)f2bf(lo[3]);
  o[4] = (short)f2bf(hi[0]); o[5] = (short)f2bf(hi[1]);
  o[6] = (short)f2bf(hi[2]); o[7] = (short)f2bf(hi[3]);
  return o;
}

// Direct global->LDS DMA, 16B per lane. LDS dest = wave-uniform base + lane*16
// (linear); swizzling is done on the per-lane GLOBAL source address.
__device__ inline void gload_lds16(const float* g, void* l) {
  __builtin_amdgcn_global_load_lds(
      (const __attribute__((address_space(1))) void*)g,
      (__attribute__((address_space(3))) void*)l, 16, 0, 0);
}

// Chunked XCD remap, nwg=512 (512%8==0 -> bijective).
__device__ inline int xcd_map(int bid) { return (bid & 7) * 64 + (bid >> 3); }

// Stage a 128x128 f32 matrix (row-major, row stride 128 f32) into linear LDS
// with per-row slot swizzle: LDS[m][c] = M[m][c ^ (m&15)] (16B-slot units).
// Each wave instr covers 2 rows (1024 B contiguous LDS).
__device__ inline void stage_swz(const float* __restrict__ src, float* lds,
                                 int wv_, int lane) {
  const int c = lane & 31;          // dest 16B slot within row
  const int rw = lane >> 5;         // 0/1: which of the 2 rows this instr
#pragma unroll
  for (int it = 0; it < 16; ++it) {
    const int m0 = it * 8 + wv_ * 2;        // wave-uniform base row
    const int m = m0 + rw;                  // this lane's row
    const int gs = c ^ (m & 15);            // swizzled source slot
    gload_lds16(src + m * 128 + gs * 4, lds + m0 * 128);
  }
}

// Read fragment row R, f32 cols [K0, K0+8) from the swizzled LDS image,
// converting to bf16x8. K0 is 32B-aligned (K0 = ks*32 + quad*8).
__device__ inline bf16x8 frag_swz(const float* lds, int R, int K0) {
  const int s0 = K0 >> 2;                   // 16B slot index (even)
  const int x = R & 15;
  f32x4 lo = *(const f32x4*)(lds + R * 128 + ((s0 ^ x) << 2));
  f32x4 hi = *(const f32x4*)(lds + R * 128 + (((s0 + 1) ^ x) << 2));
  return cvt8(lo, hi);
}

// ---------------- k_A: V[n',i] = sum_j W[k,i,j] * t_bn[n',j] ----------------
// grid 512: wg = (k<<2)|quarter; 64 rows n' = k*256 + quarter*64 + wv*16 + l16.
__global__ __launch_bounds__(256, 2) void k_A(
    const float* __restrict__ t, const float* __restrict__ W,
    const float* __restrict__ gamma1, const float* __restrict__ beta1,
    const float* __restrict__ mean1, const float* __restrict__ var1,
    unsigned short* __restrict__ V) {
  __shared__ float LW[128 * 128];   // W[k] f32, linear rows, slot-swizzled
  const int tid = threadIdx.x;
  const int wv_ = tid >> 6;
  const int lane = tid & 63;
  const int l16 = lane & 15;
  const int quad = lane >> 4;

  const int wg = xcd_map(blockIdx.x);
  const int k = wg >> 2;
  const int quarter = wg & 3;
  const int nrow = k * 256 + quarter * 64 + wv_ * 16 + l16;

  // (1) issue the W->LDS DMA first (16 instrs/wave, no VGPR round-trip)
  stage_swz(W + (size_t)k * 16384, LW, wv_, lane);

  // (2) t fragments direct from global with BN + in-register cvt (R10 path,
  // passed) — overlaps the W DMA.
  const float* tp = t + (size_t)nrow * 128;
  bf16x8 tf[4];
#pragma unroll
  for (int ks = 0; ks < 4; ++ks) {
    const int K0 = ks * 32 + quad * 8;
    f32x4 g0 = *(const f32x4*)(gamma1 + K0), g1 = *(const f32x4*)(gamma1 + K0 + 4);
    f32x4 b0 = *(const f32x4*)(beta1  + K0), b1 = *(const f32x4*)(beta1  + K0 + 4);
    f32x4 m0 = *(const f32x4*)(mean1  + K0), m1 = *(const f32x4*)(mean1  + K0 + 4);
    f32x4 v0 = *(const f32x4*)(var1   + K0), v1 = *(const f32x4*)(var1   + K0 + 4);
    f32x4 t0 = *(const f32x4*)(tp + K0),     t1 = *(const f32x4*)(tp + K0 + 4);
    f32x4 lo, hi;
    for (int q = 0; q < 4; ++q) {
      const float s0 = g0[q] * rsqrtf(v0[q] + BN_EPS);
      lo[q] = t0[q] * s0 + (b0[q] - m0[q] * s0);
      const float s1 = g1[q] * rsqrtf(v1[q] + BN_EPS);
      hi[q] = t1[q] * s1 + (b1[q] - m1[q] * s1);
    }
    tf[ks] = cvt8(lo, hi);
  }
  __syncthreads();   // drains the global_load_lds queue (vmcnt) + all waves

  // (3) MFMA: acc = mfma(Wfrag, Tfrag) -> D[i-part(row), n'-part(col)]
  f32x4 acc[8];
#pragma unroll
  for (int nt = 0; nt < 8; ++nt) acc[nt] = (f32x4){0.f, 0.f, 0.f, 0.f};

  __builtin_amdgcn_s_setprio(1);
#pragma unroll
  for (int ks = 0; ks < 4; ++ks) {
    const int K0 = ks * 32 + quad * 8;
    bf16x8 b[8];
#pragma unroll
    for (int nt = 0; nt < 8; ++nt)
      b[nt] = frag_swz(LW, nt * 16 + l16, K0);
#pragma unroll
    for (int nt = 0; nt < 8; ++nt)
      acc[nt] = __builtin_amdgcn_mfma_f32_16x16x32_bf16(b[nt], tf[ks], acc[nt], 0, 0, 0);
  }
  __builtin_amdgcn_s_setprio(0);

  // (4) lane holds i = nt*16 + quad*4 + {0..3} of row n' = nrow (R10, passed)
  const size_t np = (size_t)nrow * 128;
#pragma unroll
  for (int nt = 0; nt < 8; ++nt) {
    unsigned two[2];
    two[0] = pack2bf(acc[nt][0], acc[nt][1]);
    two[1] = pack2bf(acc[nt][2], acc[nt][3]);
    *(uint2*)(V + np + nt * 16 + quad * 4) = *(uint2*)two;
  }
}

// ---- k_B: G[a][n'] = sum_i r[low,a,i]*V[n',i]; out[n'] = sum_a h_bn[n',a]*G[a][n'] ----
// grid 512: wg = (low<<1)|half; rows kk = half*64 + wv*16 + l16, n' = kk*256+low.
__global__ __launch_bounds__(256, 2) void k_B(
    const float* __restrict__ h, const float* __restrict__ r,
    const float* __restrict__ gamma0, const float* __restrict__ beta0,
    const float* __restrict__ mean0, const float* __restrict__ var0,
    const unsigned short* __restrict__ V, float* __restrict__ out) {
  __shared__ float LR[128 * 128];   // r[low] f32, linear rows, slot-swizzled
  const int tid = threadIdx.x;
  const int wv_ = tid >> 6;
  const int lane = tid & 63;
  const int l16 = lane & 15;
  const int quad = lane >> 4;

  const int wg = xcd_map(blockIdx.x);
  const int low = wg >> 1;
  const int half = wg & 1;
  const int kk = half * 64 + wv_ * 16 + l16;
  const size_t nprow = (size_t)kk * 256 + low;

  // (1) issue the r->LDS DMA first
  stage_swz(r + (size_t)low * 16384, LR, wv_, lane);

  // (2) V fragments direct from global bf16 (R10 path, passed) — overlaps DMA
  const unsigned short* vp = V + nprow * 128;
  bf16x8 vf[4];
#pragma unroll
  for (int ks = 0; ks < 4; ++ks)
    vf[ks] = *(const bf16x8*)(vp + ks * 32 + quad * 8);
  __syncthreads();

  // (3) MFMA: acc = mfma(Rfrag, Vfrag) -> D[a-part(row), kk-part(col)]
  f32x4 acc[8];
#pragma unroll
  for (int nt = 0; nt < 8; ++nt) acc[nt] = (f32x4){0.f, 0.f, 0.f, 0.f};

  __builtin_amdgcn_s_setprio(1);
#pragma unroll
  for (int ks = 0; ks < 4; ++ks) {
    const int K0 = ks * 32 + quad * 8;
    bf16x8 b[8];
#pragma unroll
    for (int nt = 0; nt < 8; ++nt)
      b[nt] = frag_swz(LR, nt * 16 + l16, K0);
#pragma unroll
    for (int nt = 0; nt < 8; ++nt)
      acc[nt] = __builtin_amdgcn_mfma_f32_16x16x32_bf16(b[nt], vf[ks], acc[nt], 0, 0, 0);
  }
  __builtin_amdgcn_s_setprio(0);

  // (4) epilogue: lane holds G[a = nt*16+quad*4+q][n'(l16)]; dot with f32
  // h_bn, quad-reduce, write (R10, passed).
  const float* hp = h + nprow * 128;
  float s = 0.f;
#pragma unroll
  for (int nt = 0; nt < 8; ++nt) {
    const int a0 = nt * 16 + quad * 4;
    f32x4 hv = *(const f32x4*)(hp + a0);
    f32x4 g  = *(const f32x4*)(gamma0 + a0);
    f32x4 be = *(const f32x4*)(beta0  + a0);
    f32x4 mu = *(const f32x4*)(mean0  + a0);
    f32x4 va = *(const f32x4*)(var0   + a0);
    for (int q = 0; q < 4; ++q) {
      const float sc = g[q] * rsqrtf(va[q] + BN_EPS);
      const float hb = hv[q] * sc + (be[q] - mu[q] * sc);
      s += hb * acc[nt][q];
    }
  }
  s += __shfl_xor(s, 16, 64);
  s += __shfl_xor(s, 32, 64);
  if (quad == 0) out[nprow] = s;
}

extern "C" void kernel_launch(void* const* d_in, const int* in_sizes, int n_in,
                              void* d_out, int out_size, void* d_ws, size_t ws_size,
                              hipStream_t stream) {
  const float* h      = (const float*)d_in[0];
  const float* r      = (const float*)d_in[1];
  const float* t      = (const float*)d_in[2];
  const float* W      = (const float*)d_in[3];
  const float* gamma0 = (const float*)d_in[4];
  const float* beta0  = (const float*)d_in[5];
  const float* mean0  = (const float*)d_in[6];
  const float* var0   = (const float*)d_in[7];
  const float* gamma1 = (const float*)d_in[8];
  const float* beta1  = (const float*)d_in[9];
  const float* mean1  = (const float*)d_in[10];
  const float* var1   = (const float*)d_in[11];
  float* out = (float*)d_out;

  unsigned short* V = (unsigned short*)d_ws;   // 32768*128 bf16 = 8 MB

  k_A<<<512, 256, 0, stream>>>(t, W, gamma1, beta1, mean1, var1, V);
  k_B<<<512, 256, 0, stream>>>(h, r, gamma0, beta0, mean0, var0, V, out);
}

// Round 9
// 117.329 us; speedup vs baseline: 1.0417x; 1.0417x over previous
//
#include <hip/hip_runtime.h>

// TuckERInteraction: scores[n'] = sum_i u[n',i] * v[n',i]
//   v[n',i] = sum_j W[n'>>8, i, j] * t_bn[n', j]        (stage A, grouped by k = n'>>8)
//   u[n',i] = sum_a h_bn[n',a] * r[(n'&255)*128+a, i]   (stage B, grouped by low = n'&255)
// N = 32768, D = 128. Only V is materialized (bf16, 8 MB in d_ws).
//
// R13 = R4 verbatim (the session optimum, 114.5 us). Ledger of 8 measured
// variants: occupancy x2/x3, XCD swizzle, setprio, fusion (64.9 us fused
// kernel, coop overhead +75), LDS-free (-24%), 32-deep load burst,
// global_load_lds + swizzle — ALL within +-4% of this structure or worse.
// The timed region = 41.6 us poison fill (80% HBM peak, fixed) + ~60-65 us
// kernel pair (upper-bounded by R6's fused 64.9 us) + ~10 us launch/reset;
// the pair is invariant to every structural lever => practical ceiling.

typedef __attribute__((ext_vector_type(8))) short bf16x8;   // MFMA A/B fragment (8 bf16)
typedef __attribute__((ext_vector_type(4))) short s16x4;
typedef __attribute__((ext_vector_type(4))) float f32x4;

#define DPAD 136   // LDS row stride (elements)
#define BN_EPS 1e-5f

__device__ inline unsigned short f2bf(float f) {
  unsigned u = __builtin_bit_cast(unsigned, f);
  u += 0x7FFFu + ((u >> 16) & 1u);          // round-to-nearest-even
  return (unsigned short)(u >> 16);
}
__device__ inline float bf2f(unsigned short h) {
  unsigned u = ((unsigned)h) << 16;
  return __builtin_bit_cast(float, u);
}
__device__ inline unsigned pack2bf(float lo, float hi) {
  return (unsigned)f2bf(lo) | ((unsigned)f2bf(hi) << 16);
}

// ---------------- Stage A: V[n', i] = sum_j W[k,i,j] * t_bn[n', j] ----------------
// grid 256: block = (k, half); 128 rows n' = k*256 + half*128 + m
__global__ __launch_bounds__(256) void k_stageA(
    const float* __restrict__ t, const float* __restrict__ W,
    const float* __restrict__ gamma1, const float* __restrict__ beta1,
    const float* __restrict__ mean1, const float* __restrict__ var1,
    unsigned short* __restrict__ V) {
  __shared__ short LA[128 * DPAD];  // Tl[m][j] = bf16(t_bn[rowbase+m, j])
  __shared__ short LB[128 * DPAD];  // Wl[i][j] = bf16(W[k, i, j])
  const int tid = threadIdx.x;
  const int c = tid & 31;
  const int rr = tid >> 5;
  const int wv_ = tid >> 6;
  const int lane = tid & 63;
  const int l16 = lane & 15;
  const int quad = lane >> 4;

  const int k = blockIdx.x >> 1;           // [0,128)
  const int half = blockIdx.x & 1;
  const int rowbase = k * 256 + half * 128;

  f32x4 g  = *(const f32x4*)(gamma1 + c * 4);
  f32x4 be = *(const f32x4*)(beta1  + c * 4);
  f32x4 mu = *(const f32x4*)(mean1  + c * 4);
  f32x4 va = *(const f32x4*)(var1   + c * 4);
  f32x4 sc, bi;
  for (int q = 0; q < 4; ++q) {
    sc[q] = g[q] * rsqrtf(va[q] + BN_EPS);
    bi[q] = be[q] - mu[q] * sc[q];
  }
  const float* tbase = t + (size_t)rowbase * 128;
  const float* wbase = W + (size_t)k * 16384;
  for (int it = 0; it < 16; ++it) {
    const int m = it * 8 + rr;
    f32x4 tv = *(const f32x4*)(tbase + m * 128 + c * 4);
    s16x4 tb;
    for (int q = 0; q < 4; ++q) tb[q] = (short)f2bf(tv[q] * sc[q] + bi[q]);
    *(s16x4*)(&LA[m * DPAD + c * 4]) = tb;
    f32x4 wvv = *(const f32x4*)(wbase + m * 128 + c * 4);
    s16x4 wb;
    for (int q = 0; q < 4; ++q) wb[q] = (short)f2bf(wvv[q]);
    *(s16x4*)(&LB[m * DPAD + c * 4]) = wb;
  }
  __syncthreads();

  f32x4 acc[2][8];
  for (int mt = 0; mt < 2; ++mt)
    for (int nt = 0; nt < 8; ++nt) acc[mt][nt] = (f32x4){0.f, 0.f, 0.f, 0.f};

  // swapped operands: acc = mfma(Wfrag, Tfrag) -> D[i-part(row), n'-part(col)]
  for (int ks = 0; ks < 4; ++ks) {
    const int K0 = ks * 32 + quad * 8;
    bf16x8 a[2], b[8];
    for (int mt = 0; mt < 2; ++mt)
      a[mt] = *(const bf16x8*)(&LA[(wv_ * 32 + mt * 16 + l16) * DPAD + K0]);
    for (int nt = 0; nt < 8; ++nt)
      b[nt] = *(const bf16x8*)(&LB[(nt * 16 + l16) * DPAD + K0]);
    for (int mt = 0; mt < 2; ++mt)
      for (int nt = 0; nt < 8; ++nt)
        acc[mt][nt] = __builtin_amdgcn_mfma_f32_16x16x32_bf16(b[nt], a[mt], acc[mt][nt], 0, 0, 0);
  }

  // lane holds i = nt*16 + quad*4 + {0..3} of row n' = rowbase + wv*32 + mt*16 + l16
  for (int mt = 0; mt < 2; ++mt) {
    const size_t np = (size_t)(rowbase + wv_ * 32 + mt * 16 + l16) * 128;
    for (int nt = 0; nt < 8; ++nt) {
      unsigned two[2];
      two[0] = pack2bf(acc[mt][nt][0], acc[mt][nt][1]);
      two[1] = pack2bf(acc[mt][nt][2], acc[mt][nt][3]);
      *(uint2*)(V + np + nt * 16 + quad * 4) = *(uint2*)two;
    }
  }
}

// ------- Stage B + dot: out[n'] = sum_i (sum_a h_bn[n',a] r[low*128+a, i]) * V[n',i] -------
// grid 256: block = low; rows n' = kk*256 + low, kk in [0,128)
__global__ __launch_bounds__(256) void k_bdot(
    const float* __restrict__ h, const float* __restrict__ r,
    const float* __restrict__ gamma0, const float* __restrict__ beta0,
    const float* __restrict__ mean0, const float* __restrict__ var0,
    const unsigned short* __restrict__ V, float* __restrict__ out) {
  __shared__ short LA[128 * DPAD];  // Hl[kk][a] = bf16(h_bn[kk*256+low, a])
  __shared__ short LB[128 * DPAD];  // Rl[i][a]  = bf16(r[low*128+a, i])   (transposed)
  const int tid = threadIdx.x;
  const int c = tid & 31;
  const int rr = tid >> 5;
  const int wv_ = tid >> 6;
  const int lane = tid & 63;
  const int l16 = lane & 15;
  const int quad = lane >> 4;

  const int low = blockIdx.x;              // [0,256)

  f32x4 g  = *(const f32x4*)(gamma0 + c * 4);
  f32x4 be = *(const f32x4*)(beta0  + c * 4);
  f32x4 mu = *(const f32x4*)(mean0  + c * 4);
  f32x4 va = *(const f32x4*)(var0   + c * 4);
  f32x4 sc, bi;
  for (int q = 0; q < 4; ++q) {
    sc[q] = g[q] * rsqrtf(va[q] + BN_EPS);
    bi[q] = be[q] - mu[q] * sc[q];
  }
  for (int it = 0; it < 16; ++it) {
    const int kk = it * 8 + rr;
    f32x4 hv = *(const f32x4*)(h + ((size_t)(kk * 256 + low)) * 128 + c * 4);
    s16x4 hb;
    for (int q = 0; q < 4; ++q) hb[q] = (short)f2bf(hv[q] * sc[q] + bi[q]);
    *(s16x4*)(&LA[kk * DPAD + c * 4]) = hb;
  }
  // transpose-stage r: thread owns 4x4 block (rows a0..a0+3, cols 4c..4c+3)
  for (int it = 0; it < 4; ++it) {
    const int a0 = it * 32 + rr * 4;
    f32x4 rv[4];
    for (int v = 0; v < 4; ++v)
      rv[v] = *(const f32x4*)(r + ((size_t)(low * 128 + a0 + v)) * 128 + c * 4);
    for (int u = 0; u < 4; ++u) {
      s16x4 w;
      for (int v = 0; v < 4; ++v) w[v] = (short)f2bf(rv[v][u]);
      *(s16x4*)(&LB[(c * 4 + u) * DPAD + a0]) = w;
    }
  }
  __syncthreads();

  f32x4 acc[2][8];
  for (int mt = 0; mt < 2; ++mt)
    for (int nt = 0; nt < 8; ++nt) acc[mt][nt] = (f32x4){0.f, 0.f, 0.f, 0.f};

  // swapped operands: acc = mfma(Rfrag, Hfrag) -> D[i-part(row), kk-part(col)]
  for (int ks = 0; ks < 4; ++ks) {
    const int K0 = ks * 32 + quad * 8;
    bf16x8 a[2], b[8];
    for (int mt = 0; mt < 2; ++mt)
      a[mt] = *(const bf16x8*)(&LA[(wv_ * 32 + mt * 16 + l16) * DPAD + K0]);
    for (int nt = 0; nt < 8; ++nt)
      b[nt] = *(const bf16x8*)(&LB[(nt * 16 + l16) * DPAD + K0]);
    for (int mt = 0; mt < 2; ++mt)
      for (int nt = 0; nt < 8; ++nt)
        acc[mt][nt] = __builtin_amdgcn_mfma_f32_16x16x32_bf16(b[nt], a[mt], acc[mt][nt], 0, 0, 0);
  }

  // fused dot: lane holds u[n', i=nt*16+quad*4+q] fp32 for row n' = kk*256+low,
  // kk = wv*32 + mt*16 + l16. Load matching V bf16, FMA, reduce across quads.
  for (int mt = 0; mt < 2; ++mt) {
    const int kk = wv_ * 32 + mt * 16 + l16;
    const size_t np = ((size_t)kk * 256 + low) * 128;
    float s = 0.f;
    for (int nt = 0; nt < 8; ++nt) {
      const uint2 vv = *(const uint2*)(V + np + nt * 16 + quad * 4);
      s += acc[mt][nt][0] * bf2f((unsigned short)(vv.x & 0xFFFFu));
      s += acc[mt][nt][1] * bf2f((unsigned short)(vv.x >> 16));
      s += acc[mt][nt][2] * bf2f((unsigned short)(vv.y & 0xFFFFu));
      s += acc[mt][nt][3] * bf2f((unsigned short)(vv.y >> 16));
    }
    s += __shfl_xor(s, 16, 64);
    s += __shfl_xor(s, 32, 64);
    if (quad == 0) out[(size_t)kk * 256 + low] = s;
  }
}

extern "C" void kernel_launch(void* const* d_in, const int* in_sizes, int n_in,
                              void* d_out, int out_size, void* d_ws, size_t ws_size,
                              hipStream_t stream) {
  const float* h      = (const float*)d_in[0];
  const float* r      = (const float*)d_in[1];
  const float* t      = (const float*)d_in[2];
  const float* W      = (const float*)d_in[3];
  const float* gamma0 = (const float*)d_in[4];
  const float* beta0  = (const float*)d_in[5];
  const float* mean0  = (const float*)d_in[6];
  const float* var0   = (const float*)d_in[7];
  const float* gamma1 = (const float*)d_in[8];
  const float* beta1  = (const float*)d_in[9];
  const float* mean1  = (const float*)d_in[10];
  const float* var1   = (const float*)d_in[11];
  float* out = (float*)d_out;

  unsigned short* V = (unsigned short*)d_ws;   // 32768*128 bf16 = 8 MB

  k_stageA<<<256, 256, 0, stream>>>(t, W, gamma1, beta1, mean1, var1, V);
  k_bdot<<<256, 256, 0, stream>>>(h, r, gamma0, beta0, mean0, var0, V, out);
}